// Round 10
// baseline (56.595 us; speedup 1.0000x reference)
//
#include <hip/hip_runtime.h>
#include <hip/hip_fp16.h>

// NCC loss, window 9, zero-padded separable box sums.
// Shapes: (2,1,160,160,160) f32. Output: scalar f32.
//
// K1: per d-slice fused W+H 2D 9x9 box sum of 5 product channels.
//     TH=16 tile (1.5x h-halo overcompute, was 2x). H-stage = 4-row
//     sliding window per thread (12 ds_read_b64 per ch for 8 voxels =
//     1.5 reads/voxel, was 4.5). wsum fp16 LDS 38.4 KB; A in FP8 e4m3.
//     Bijective XCD swizzle (3200 = 8*400).
// K2: D-axis sliding-window sum, 4 voxels/thread via 4B uint fp8 loads,
//     SEG=10 -> 800 blocks.
// ws layout: A8[2][5][VOL] bytes (41 MB) | partials[800] f32

#define DIM 160
#define HW  (160 * 160)
#define VOL (160 * 160 * 160)
#define NBATCH 2
#define TH 16                  // output rows per K1 block
#define SR 24                  // staged rows = TH + 8
#define THB 320
#define SEG 10
#define NSEG (DIM / SEG)       // 16

struct __align__(16) h8 { __half2 a, b, c, d; };
typedef float v2f __attribute__((ext_vector_type(2)));

__device__ inline float4 dec8(unsigned int u) {
    v2f lo = __builtin_amdgcn_cvt_pk_f32_fp8((int)u, false);
    v2f hi = __builtin_amdgcn_cvt_pk_f32_fp8((int)u, true);
    return make_float4(lo[0], lo[1], hi[0], hi[1]);
}

__device__ inline unsigned short enc2(float a, float b) {
    return (unsigned short)(__builtin_amdgcn_cvt_pk_fp8_f32(a, b, 0, false) & 0xffff);
}

__global__ __launch_bounds__(THB) void k1_boxsum2d(const float* __restrict__ I,
                                                   const float* __restrict__ J,
                                                   unsigned char* __restrict__ A8) {
    __shared__ __half wsl[5][SR][DIM];   // 38400 B

    const int tid = threadIdx.x;
    // bijective XCD swizzle over 3200 blocks (8 * 400)
    const int orig = blockIdx.x;
    const int wgid = (orig & 7) * 400 + (orig >> 3);
    const int ty = wgid % 10;
    const int rest = wgid / 10;
    const int d = rest % DIM;
    const int batch = rest / DIM;
    const int h0 = ty * TH;
    const float* Ib = I + (size_t)batch * VOL + (size_t)d * HW;
    const float* Jb = J + (size_t)batch * VOL + (size_t)d * HW;

    // ---- W-stage: 480 tasks = 24 rows x 20 groups of 8 outputs ----
    for (int t = tid; t < 480; t += THB) {
        const int r = t / 20, g = t % 20;
        const int gh = h0 - 4 + r;
        const int gw = 8 * g - 4;        // 4-aligned
        __half* wrow = &wsl[0][0][0] + (r * DIM + 8 * g);

        if (gh < 0 || gh >= DIM) {
            const __half2 hz = __float2half2_rn(0.f);
            h8 z; z.a = hz; z.b = hz; z.c = hz; z.d = hz;
#pragma unroll
            for (int ch = 0; ch < 5; ++ch)
                *(h8*)(wrow + ch * (SR * DIM)) = z;
        } else {
            const float* pI = Ib + gh * DIM;
            const float* pJ = Jb + gh * DIM;
            float a[16], b[16];
#pragma unroll
            for (int q = 0; q < 4; ++q) {
                int c0 = gw + 4 * q;     // quad fully in [0,160) or fully out
                if (c0 >= 0 && c0 < DIM) {
                    *(float4*)&a[4 * q] = *(const float4*)(pI + c0);
                    *(float4*)&b[4 * q] = *(const float4*)(pJ + c0);
                } else {
                    *(float4*)&a[4 * q] = make_float4(0.f, 0.f, 0.f, 0.f);
                    *(float4*)&b[4 * q] = make_float4(0.f, 0.f, 0.f, 0.f);
                }
            }
#define PROC(CH, VAL)                                                       \
            {                                                               \
                float o[8];                                                 \
                float ss = 0.f;                                             \
                _Pragma("unroll")                                           \
                for (int k = 0; k < 9; ++k) { ss += (VAL); }                \
                o[0] = ss;                                                  \
                _Pragma("unroll")                                           \
                for (int j = 1; j < 8; ++j) {                               \
                    int k = j + 8; float add_ = (VAL);                      \
                    k = j - 1;     float sub_ = (VAL);                      \
                    ss += add_ - sub_;                                      \
                    o[j] = ss;                                              \
                }                                                           \
                h8 v;                                                       \
                v.a = __floats2half2_rn(o[0], o[1]);                        \
                v.b = __floats2half2_rn(o[2], o[3]);                        \
                v.c = __floats2half2_rn(o[4], o[5]);                        \
                v.d = __floats2half2_rn(o[6], o[7]);                        \
                *(h8*)(wrow + CH * (SR * DIM)) = v;                         \
            }
            PROC(0, a[k])
            PROC(1, b[k])
            PROC(2, a[k] * a[k])
            PROC(3, b[k] * b[k])
            PROC(4, a[k] * b[k])
#undef PROC
        }
    }
    __syncthreads();

    // ---- H-stage: thread = (row-quad rq, half2-col wp), 4-row slide ----
    {
        const int wp = tid % 80;         // half2 column
        const int rq = tid / 80;         // 0..3 -> rows 4rq..4rq+3
        const size_t obase = (size_t)batch * 5 * VOL + (size_t)d * HW +
                             (size_t)(h0 + 4 * rq) * DIM + 2 * wp;
#pragma unroll
        for (int ch = 0; ch < 5; ++ch) {
            const __half2* col = (const __half2*)&wsl[ch][4 * rq][0] + wp;
            __half2 c[12];
#pragma unroll
            for (int k = 0; k < 12; ++k) c[k] = col[k * (DIM / 2)];
            __half2 s = c[0];
#pragma unroll
            for (int k = 1; k < 9; ++k) s = __hadd2(s, c[k]);
            unsigned char* Ao = A8 + obase + (size_t)ch * VOL;
            {
                float2 f = __half22float2(s);
                *(unsigned short*)Ao = enc2(f.x, f.y);
            }
#pragma unroll
            for (int j = 1; j < 4; ++j) {
                s = __hadd2(__hsub2(s, c[j - 1]), c[j + 8]);
                float2 f = __half22float2(s);
                *(unsigned short*)(Ao + (size_t)j * DIM) = enc2(f.x, f.y);
            }
        }
    }
}

__device__ inline void cc_accum(float s0, float s1, float s2, float s3,
                                float s4, float& acc) {
    const float inv_wsz = 1.0f / 729.0f;
    float cross = s4 - s0 * s1 * inv_wsz;
    float Ivar  = s2 - s0 * s0 * inv_wsz;
    float Jvar  = s3 - s1 * s1 * inv_wsz;
    float cc = cross * cross * __builtin_amdgcn_rcpf(Ivar * Jvar + 1e-5f);
    acc += fminf(fmaxf(cc, 0.0f), 1.0f);
}

__global__ __launch_bounds__(256) void k2_dsum_final(const unsigned char* __restrict__ A8,
                                                     float* __restrict__ partial) {
    const int batch = blockIdx.y;
    const unsigned int* B = (const unsigned int*)(A8 + (size_t)batch * 5 * VOL);
    const int PLW = VOL / 4;                 // uint plane stride
    const int HWW = HW / 4;                  // uint slice stride
    int t = blockIdx.x * 256 + threadIdx.x;  // < 40*160*16 = 102400
    int wq = t % 40;
    int rest = t / 40;
    int h = rest % DIM;
    int seg = rest / DIM;                    // 0..15
    int d0 = seg * SEG;
    const int base = h * 40 + wq;

    float4 s0 = {0,0,0,0}, s1 = {0,0,0,0}, s2 = {0,0,0,0},
           s3 = {0,0,0,0}, s4 = {0,0,0,0};
#define ACC4(sv, ch, idx, sgn)                                              \
    {                                                                       \
        float4 v_ = dec8(B[(ch) * PLW + (idx)]);                            \
        sv.x sgn v_.x; sv.y sgn v_.y; sv.z sgn v_.z; sv.w sgn v_.w;         \
    }
#pragma unroll
    for (int k = -4; k <= 4; ++k) {
        int dd = d0 + k;
        if (dd >= 0) {
            int idx = base + dd * HWW;
            ACC4(s0, 0, idx, +=) ACC4(s1, 1, idx, +=) ACC4(s2, 2, idx, +=)
            ACC4(s3, 3, idx, +=) ACC4(s4, 4, idx, +=)
        }
    }

    float acc = 0.f;
    for (int d = d0; d < d0 + SEG; ++d) {
        cc_accum(s0.x, s1.x, s2.x, s3.x, s4.x, acc);
        cc_accum(s0.y, s1.y, s2.y, s3.y, s4.y, acc);
        cc_accum(s0.z, s1.z, s2.z, s3.z, s4.z, acc);
        cc_accum(s0.w, s1.w, s2.w, s3.w, s4.w, acc);
        int lead = d + 5, trail = d - 4;
        if (lead < DIM) {
            int li = base + lead * HWW;
            ACC4(s0, 0, li, +=) ACC4(s1, 1, li, +=) ACC4(s2, 2, li, +=)
            ACC4(s3, 3, li, +=) ACC4(s4, 4, li, +=)
        }
        if (trail >= 0) {
            int ti = base + trail * HWW;
            ACC4(s0, 0, ti, -=) ACC4(s1, 1, ti, -=) ACC4(s2, 2, ti, -=)
            ACC4(s3, 3, ti, -=) ACC4(s4, 4, ti, -=)
        }
    }
#undef ACC4

#pragma unroll
    for (int off = 32; off > 0; off >>= 1) acc += __shfl_down(acc, off);
    __shared__ float ws4[4];
    if ((threadIdx.x & 63) == 0) ws4[threadIdx.x >> 6] = acc;
    __syncthreads();
    if (threadIdx.x == 0)
        partial[batch * 400 + blockIdx.x] = ws4[0] + ws4[1] + ws4[2] + ws4[3];
}

__global__ __launch_bounds__(256) void final_reduce(const float* __restrict__ partial,
                                                    int n, float* __restrict__ out) {
    float a = 0.f;
    for (int i = threadIdx.x; i < n; i += 256) a += partial[i];
#pragma unroll
    for (int off = 32; off > 0; off >>= 1) a += __shfl_down(a, off);
    __shared__ float ws4[4];
    if ((threadIdx.x & 63) == 0) ws4[threadIdx.x >> 6] = a;
    __syncthreads();
    if (threadIdx.x == 0)
        out[0] = 1.0f - (ws4[0] + ws4[1] + ws4[2] + ws4[3]) *
                            (1.0f / (float)(NBATCH * VOL));
}

extern "C" void kernel_launch(void* const* d_in, const int* in_sizes, int n_in,
                              void* d_out, int out_size, void* d_ws, size_t ws_size,
                              hipStream_t stream) {
    const float* I = (const float*)d_in[0];
    const float* J = (const float*)d_in[1];
    float* out = (float*)d_out;

    unsigned char* A8 = (unsigned char*)d_ws;           // [2][5][VOL] fp8
    float* partial = (float*)(A8 + (size_t)NBATCH * 5 * VOL); // [800]

    k1_boxsum2d<<<(DIM / TH) * DIM * NBATCH, THB, 0, stream>>>(I, J, A8);
    dim3 g2(400, NBATCH);                  // 800 blocks
    k2_dsum_final<<<g2, 256, 0, stream>>>(A8, partial);
    final_reduce<<<1, 256, 0, stream>>>(partial, NBATCH * 400, out);
}

// Round 11
// 55.596 us; speedup vs baseline: 1.0180x; 1.0180x over previous
//
#include <hip/hip_runtime.h>
#include <hip/hip_fp16.h>

// NCC loss, window 9, zero-padded separable box sums.
// Shapes: (2,1,160,160,160) f32. Output: scalar f32.
//
// K1: fused W+H 2D 9x9 box sum of 5 product channels, TWO d-slices per
//     block, software-pipelined: slice d+1's global loads are issued into
//     registers right after the first barrier and fly under slice d's
//     entire H-stage (T14 async-stage split; K1 is latency-bound, rounds
//     6-10 evidence). TH=8 geometry: exactly 320 W-tasks, LDS 25.6 KB.
//     wsum fp16; intermediate A in FP8 e4m3 (sums <= 81 < 448).
//     Bijective XCD swizzle; consecutive wgids share halo rows in-XCD.
// K2: D-axis sliding-window sum, 4 voxels/thread via 4B uint fp8 loads,
//     SEG=10 -> 800 blocks.
// ws layout: A8[2][5][VOL] bytes (41 MB) | partials[800] f32

#define DIM 160
#define HW  (160 * 160)
#define VOL (160 * 160 * 160)
#define NBATCH 2
#define TH 8                   // output rows per slice per block
#define SR 16                  // staged rows = TH + 8
#define THB 320
#define SEG 10
#define NSEG (DIM / SEG)       // 16

struct __align__(16) h8 { __half2 a, b, c, d; };
struct __align__(8) h4 { __half2 a, b; };
typedef float v2f __attribute__((ext_vector_type(2)));

__device__ inline float4 dec8(unsigned int u) {
    v2f lo = __builtin_amdgcn_cvt_pk_f32_fp8((int)u, false);
    v2f hi = __builtin_amdgcn_cvt_pk_f32_fp8((int)u, true);
    return make_float4(lo[0], lo[1], hi[0], hi[1]);
}

__device__ inline unsigned int enc8(float a, float b, float c, float d) {
    int u = __builtin_amdgcn_cvt_pk_fp8_f32(a, b, 0, false);
    u = __builtin_amdgcn_cvt_pk_fp8_f32(c, d, u, true);
    return (unsigned int)u;
}

__global__ __launch_bounds__(THB) void k1_boxsum2d(const float* __restrict__ I,
                                                   const float* __restrict__ J,
                                                   unsigned char* __restrict__ A8) {
    __shared__ __half wsl[5][SR][DIM];   // 25600 B

    const int tid = threadIdx.x;
    // bijective XCD swizzle over 3200 blocks (8 * 400); consecutive wgids
    // = same d-pair, neighboring h-tiles -> shared halo rows stay in-XCD.
    const int orig = blockIdx.x;
    const int wgid = (orig & 7) * 400 + (orig >> 3);
    const int ty = wgid % 20;
    const int rest = wgid / 20;
    const int dz = rest % 80;
    const int batch = rest / 80;
    const int h0 = ty * TH;
    const int d0 = 2 * dz;
    const float* Ib = I + (size_t)batch * VOL;
    const float* Jb = J + (size_t)batch * VOL;

    // W-task geometry (identical for both slices)
    const int r = tid / 20, g = tid % 20;
    const int gh = h0 - 4 + r;
    const int gw = 8 * g - 4;            // 4-aligned
    const bool rowok = (gh >= 0) && (gh < DIM);

    float a[16], b[16], a2[16], b2[16];

#define LOADROW(d, A_, B_)                                                  \
    if (rowok) {                                                            \
        const float* pI = Ib + (size_t)(d) * HW + gh * DIM;                 \
        const float* pJ = Jb + (size_t)(d) * HW + gh * DIM;                 \
        _Pragma("unroll")                                                   \
        for (int q = 0; q < 4; ++q) {                                       \
            int c0 = gw + 4 * q;   /* quad fully in [0,160) or fully out */ \
            if (c0 >= 0 && c0 < DIM) {                                      \
                *(float4*)&A_[4 * q] = *(const float4*)(pI + c0);           \
                *(float4*)&B_[4 * q] = *(const float4*)(pJ + c0);           \
            } else {                                                        \
                *(float4*)&A_[4 * q] = make_float4(0.f, 0.f, 0.f, 0.f);     \
                *(float4*)&B_[4 * q] = make_float4(0.f, 0.f, 0.f, 0.f);     \
            }                                                               \
        }                                                                   \
    }

#define WSTAGE(A_, B_)                                                      \
    {                                                                       \
        __half* wrow = &wsl[0][0][0] + (r * DIM + 8 * g);                   \
        if (!rowok) {                                                       \
            const __half2 hz = __float2half2_rn(0.f);                       \
            h8 z; z.a = hz; z.b = hz; z.c = hz; z.d = hz;                   \
            _Pragma("unroll")                                               \
            for (int ch = 0; ch < 5; ++ch)                                  \
                *(h8*)(wrow + ch * (SR * DIM)) = z;                         \
        } else {                                                            \
            PROC(0, A_[k], wrow)                                            \
            PROC(1, B_[k], wrow)                                            \
            PROC(2, A_[k] * A_[k], wrow)                                    \
            PROC(3, B_[k] * B_[k], wrow)                                    \
            PROC(4, A_[k] * B_[k], wrow)                                    \
        }                                                                   \
    }

#define PROC(CH, VAL, WROW)                                                 \
    {                                                                       \
        float o[8];                                                         \
        float ss = 0.f;                                                     \
        _Pragma("unroll")                                                   \
        for (int k = 0; k < 9; ++k) { ss += (VAL); }                        \
        o[0] = ss;                                                          \
        _Pragma("unroll")                                                   \
        for (int j = 1; j < 8; ++j) {                                       \
            int k = j + 8; float add_ = (VAL);                              \
            k = j - 1;     float sub_ = (VAL);                              \
            ss += add_ - sub_;                                              \
            o[j] = ss;                                                      \
        }                                                                   \
        h8 v;                                                               \
        v.a = __floats2half2_rn(o[0], o[1]);                                \
        v.b = __floats2half2_rn(o[2], o[3]);                                \
        v.c = __floats2half2_rn(o[4], o[5]);                                \
        v.d = __floats2half2_rn(o[6], o[7]);                                \
        *(h8*)(WROW + CH * (SR * DIM)) = v;                                 \
    }

    // H-stage: thread = (w-quad q=tid%40, row r8=tid/40), 9x b64 reads,
    // one 4B fp8-uint store per channel.
#define HSTAGE(d)                                                           \
    {                                                                       \
        const int q = tid % 40, r8 = tid / 40;                              \
        const int wp0 = 2 * q;                                              \
        const size_t ob = (size_t)batch * 5 * VOL + (size_t)(d) * HW +      \
                          (size_t)(h0 + r8) * DIM + 4 * q;                  \
        _Pragma("unroll")                                                   \
        for (int ch = 0; ch < 5; ++ch) {                                    \
            const __half2* col = (const __half2*)&wsl[ch][r8][0] + wp0;     \
            h4 v = *(const h4*)col;                                         \
            __half2 sa = v.a, sb = v.b;                                     \
            _Pragma("unroll")                                               \
            for (int k = 1; k < 9; ++k) {                                   \
                h4 u = *(const h4*)(col + k * (DIM / 2));                   \
                sa = __hadd2(sa, u.a);                                      \
                sb = __hadd2(sb, u.b);                                      \
            }                                                               \
            float2 f0 = __half22float2(sa);                                 \
            float2 f1 = __half22float2(sb);                                 \
            *(unsigned int*)(A8 + ob + (size_t)ch * VOL) =                  \
                enc8(f0.x, f0.y, f1.x, f1.y);                               \
        }                                                                   \
    }

    // ---- pipelined 2-slice schedule ----
    LOADROW(d0, a, b)
    WSTAGE(a, b)
    __syncthreads();
    LOADROW(d0 + 1, a2, b2)      // issue early: flies under H(d0)
    HSTAGE(d0)
    __syncthreads();             // wsl consumed; loads drained here
    WSTAGE(a2, b2)
    __syncthreads();
    HSTAGE(d0 + 1)

#undef LOADROW
#undef WSTAGE
#undef PROC
#undef HSTAGE
}

__device__ inline void cc_accum(float s0, float s1, float s2, float s3,
                                float s4, float& acc) {
    const float inv_wsz = 1.0f / 729.0f;
    float cross = s4 - s0 * s1 * inv_wsz;
    float Ivar  = s2 - s0 * s0 * inv_wsz;
    float Jvar  = s3 - s1 * s1 * inv_wsz;
    float cc = cross * cross * __builtin_amdgcn_rcpf(Ivar * Jvar + 1e-5f);
    acc += fminf(fmaxf(cc, 0.0f), 1.0f);
}

__global__ __launch_bounds__(256) void k2_dsum_final(const unsigned char* __restrict__ A8,
                                                     float* __restrict__ partial) {
    const int batch = blockIdx.y;
    const unsigned int* B = (const unsigned int*)(A8 + (size_t)batch * 5 * VOL);
    const int PLW = VOL / 4;                 // uint plane stride
    const int HWW = HW / 4;                  // uint slice stride
    int t = blockIdx.x * 256 + threadIdx.x;  // < 40*160*16 = 102400
    int wq = t % 40;
    int rest = t / 40;
    int h = rest % DIM;
    int seg = rest / DIM;                    // 0..15
    int d0 = seg * SEG;
    const int base = h * 40 + wq;

    float4 s0 = {0,0,0,0}, s1 = {0,0,0,0}, s2 = {0,0,0,0},
           s3 = {0,0,0,0}, s4 = {0,0,0,0};
#define ACC4(sv, ch, idx, sgn)                                              \
    {                                                                       \
        float4 v_ = dec8(B[(ch) * PLW + (idx)]);                            \
        sv.x sgn v_.x; sv.y sgn v_.y; sv.z sgn v_.z; sv.w sgn v_.w;         \
    }
#pragma unroll
    for (int k = -4; k <= 4; ++k) {
        int dd = d0 + k;
        if (dd >= 0) {
            int idx = base + dd * HWW;
            ACC4(s0, 0, idx, +=) ACC4(s1, 1, idx, +=) ACC4(s2, 2, idx, +=)
            ACC4(s3, 3, idx, +=) ACC4(s4, 4, idx, +=)
        }
    }

    float acc = 0.f;
    for (int d = d0; d < d0 + SEG; ++d) {
        cc_accum(s0.x, s1.x, s2.x, s3.x, s4.x, acc);
        cc_accum(s0.y, s1.y, s2.y, s3.y, s4.y, acc);
        cc_accum(s0.z, s1.z, s2.z, s3.z, s4.z, acc);
        cc_accum(s0.w, s1.w, s2.w, s3.w, s4.w, acc);
        int lead = d + 5, trail = d - 4;
        if (lead < DIM) {
            int li = base + lead * HWW;
            ACC4(s0, 0, li, +=) ACC4(s1, 1, li, +=) ACC4(s2, 2, li, +=)
            ACC4(s3, 3, li, +=) ACC4(s4, 4, li, +=)
        }
        if (trail >= 0) {
            int ti = base + trail * HWW;
            ACC4(s0, 0, ti, -=) ACC4(s1, 1, ti, -=) ACC4(s2, 2, ti, -=)
            ACC4(s3, 3, ti, -=) ACC4(s4, 4, ti, -=)
        }
    }
#undef ACC4

#pragma unroll
    for (int off = 32; off > 0; off >>= 1) acc += __shfl_down(acc, off);
    __shared__ float ws4[4];
    if ((threadIdx.x & 63) == 0) ws4[threadIdx.x >> 6] = acc;
    __syncthreads();
    if (threadIdx.x == 0)
        partial[batch * 400 + blockIdx.x] = ws4[0] + ws4[1] + ws4[2] + ws4[3];
}

__global__ __launch_bounds__(256) void final_reduce(const float* __restrict__ partial,
                                                    int n, float* __restrict__ out) {
    float a = 0.f;
    for (int i = threadIdx.x; i < n; i += 256) a += partial[i];
#pragma unroll
    for (int off = 32; off > 0; off >>= 1) a += __shfl_down(a, off);
    __shared__ float ws4[4];
    if ((threadIdx.x & 63) == 0) ws4[threadIdx.x >> 6] = a;
    __syncthreads();
    if (threadIdx.x == 0)
        out[0] = 1.0f - (ws4[0] + ws4[1] + ws4[2] + ws4[3]) *
                            (1.0f / (float)(NBATCH * VOL));
}

extern "C" void kernel_launch(void* const* d_in, const int* in_sizes, int n_in,
                              void* d_out, int out_size, void* d_ws, size_t ws_size,
                              hipStream_t stream) {
    const float* I = (const float*)d_in[0];
    const float* J = (const float*)d_in[1];
    float* out = (float*)d_out;

    unsigned char* A8 = (unsigned char*)d_ws;           // [2][5][VOL] fp8
    float* partial = (float*)(A8 + (size_t)NBATCH * 5 * VOL); // [800]

    k1_boxsum2d<<<20 * 80 * NBATCH, THB, 0, stream>>>(I, J, A8);
    dim3 g2(400, NBATCH);                  // 800 blocks
    k2_dsum_final<<<g2, 256, 0, stream>>>(A8, partial);
    final_reduce<<<1, 256, 0, stream>>>(partial, NBATCH * 400, out);
}